// Round 2
// baseline (153.912 us; speedup 1.0000x reference)
//
#include <hip/hip_runtime.h>
#include <hip/hip_bf16.h>

// Fused causal attention block for MI355X (gfx950).
// Pipeline: cvt(x) | transpose(Wqkv) | transpose(Wo) -> GEMM1(qkv) -> attn -> GEMM2(out)
// All matmuls use v_mfma_f32_16x16x32_bf16 with f32 accumulation.
// Workspace usage: 28 MB (xb 4MB | WqkvT 6MB | WoT 2MB | qkv 12MB | y 4MB).

using u16 = unsigned short;
typedef __attribute__((ext_vector_type(8))) __bf16 bf16x8;      // 8 bf16 = 4 VGPR (MFMA A/B frag)
typedef __attribute__((ext_vector_type(8))) unsigned short u16x8;
typedef __attribute__((ext_vector_type(4))) float f32x4;        // MFMA C/D frag

__device__ __forceinline__ u16 f2bf(float f) {
  union { float f; unsigned u; } v; v.f = f;
  unsigned r = v.u + 0x7FFFu + ((v.u >> 16) & 1u);  // round-to-nearest-even
  return (u16)(r >> 16);
}

__device__ __forceinline__ void gload_lds16(const void* g, void* l) {
  __builtin_amdgcn_global_load_lds((const __attribute__((address_space(1))) void*)g,
                                   (__attribute__((address_space(3))) void*)l, 16, 0, 0);
}

__device__ __forceinline__ f32x4 mfma16(bf16x8 a, bf16x8 b, f32x4 c) {
  return __builtin_amdgcn_mfma_f32_16x16x32_bf16(a, b, c, 0, 0, 0);
}

// ---------------- f32 -> bf16 straight convert ----------------
__global__ __launch_bounds__(256) void cvt_bf16_kernel(const float* __restrict__ in,
                                                       u16* __restrict__ out, int n) {
  int i = (blockIdx.x * 256 + threadIdx.x) * 8;
  if (i >= n) return;
  float4 a = *(const float4*)(in + i);
  float4 b = *(const float4*)(in + i + 4);
  u16x8 r;
  r[0] = f2bf(a.x); r[1] = f2bf(a.y); r[2] = f2bf(a.z); r[3] = f2bf(a.w);
  r[4] = f2bf(b.x); r[5] = f2bf(b.y); r[6] = f2bf(b.z); r[7] = f2bf(b.w);
  *(u16x8*)(out + i) = r;
}

// ---------------- f32 [R][C] -> bf16 [C][R] transpose-convert ----------------
__global__ __launch_bounds__(256) void transpose_bf16_kernel(const float* __restrict__ in,
                                                             u16* __restrict__ out,
                                                             int R, int C) {
  __shared__ u16 tile[32][33];
  const int c0 = blockIdx.x * 32, r0 = blockIdx.y * 32;
  const int tx = threadIdx.x & 31, ty = threadIdx.x >> 5;
#pragma unroll
  for (int rr = ty; rr < 32; rr += 8)
    tile[rr][tx] = f2bf(in[(size_t)(r0 + rr) * C + (c0 + tx)]);
  __syncthreads();
#pragma unroll
  for (int rr = ty; rr < 32; rr += 8)
    out[(size_t)(c0 + rr) * R + (r0 + tx)] = tile[tx][rr];
}

// ---------------- bf16 GEMM, C[M][N] = A[M][K] * Bt[N][K]^T ----------------
// m97 structure: 128x128 tile, BK=32, 4 waves (2x2 of 64x64), global_load_lds w=16,
// 2-phase double buffer, one barrier per K-step.
template <typename OutT>
__global__ __launch_bounds__(256) void gemm_bt_kernel(const u16* __restrict__ A,
                                                      const u16* __restrict__ Bt,
                                                      OutT* __restrict__ C,
                                                      int M, int N, int K) {
  constexpr int BM = 128, BN = 128, BK = 32;
  __shared__ u16 As[2][BM * BK];
  __shared__ u16 Bs[2][BN * BK];
  const int tid = threadIdx.x;
  const int lane = tid & 63, wid = tid >> 6;
  const int l16 = lane & 15, l4 = lane >> 4;
  const int wr = (wid >> 1) * 64, wc = (wid & 1) * 64;
  const long bm = (long)blockIdx.x * BM, bn = (long)blockIdx.y * BN;

  f32x4 acc[4][4] = {};
  const int KT = K / BK;

  auto stage = [&](int buf, int kt) {
    const int k0 = kt * BK;
#pragma unroll
    for (int half = 0; half < 2; ++half) {
      int t = half * 256 + tid;
      int row = t >> 2, c8 = (t & 3) << 3;                 // 4 x 16B chunks / 64B row
      gload_lds16(A + (bm + row) * (size_t)K + k0 + c8, &As[buf][row * BK + c8]);
    }
#pragma unroll
    for (int half = 0; half < 2; ++half) {
      int t = half * 256 + tid;
      int row = t >> 2, c8 = (t & 3) << 3;
      gload_lds16(Bt + (bn + row) * (size_t)K + k0 + c8, &Bs[buf][row * BK + c8]);
    }
  };

  stage(0, 0);
  __syncthreads();
  int cur = 0;
  for (int kt = 0; kt < KT; ++kt) {
    if (kt + 1 < KT) stage(cur ^ 1, kt + 1);  // prefetch next K-tile into other buffer
    bf16x8 af[4], bfr[4];
#pragma unroll
    for (int m = 0; m < 4; ++m)   // A frag: row = l16, k-octet = l4
      af[m] = *(const bf16x8*)&As[cur][(wr + m * 16 + l16) * BK + l4 * 8];
#pragma unroll
    for (int n = 0; n < 4; ++n)   // B frag from Bt rows: col = l16, k-octet = l4
      bfr[n] = *(const bf16x8*)&Bs[cur][(wc + n * 16 + l16) * BK + l4 * 8];
#pragma unroll
    for (int m = 0; m < 4; ++m)
#pragma unroll
      for (int n = 0; n < 4; ++n)
        acc[m][n] = mfma16(af[m], bfr[n], acc[m][n]);
    __syncthreads();
    cur ^= 1;
  }

  // C/D layout: col = lane&15, row = (lane>>4)*4 + j  [verified m89/m91]
#pragma unroll
  for (int m = 0; m < 4; ++m) {
    const long row0 = bm + wr + m * 16 + l4 * 4;
#pragma unroll
    for (int n = 0; n < 4; ++n) {
      const long col = bn + wc + n * 16 + l16;
#pragma unroll
      for (int j = 0; j < 4; ++j) {
        float v = acc[m][n][j];
        if constexpr (sizeof(OutT) == 2)
          C[(row0 + j) * N + col] = (OutT)f2bf(v);
        else
          C[(row0 + j) * N + col] = (OutT)v;
      }
    }
  }
}

// ---------------- causal flash attention (double-buffered) ----------------
// qkv: [T][3072] bf16 (Q at h*64, K at 1024+h*64, V at 2048+h*64), y: [T][1024] bf16.
// Block = 64 queries x 1 head, 4 waves (16 q-rows each); KV tiles of 64 keys.
// K staged via global_load_lds (pre-swizzled source, XOR-swizzled reads).
// V prefetched to regs, written transposed AFTER compute (T14 async split);
// each ds_write_b16 instruction covers one contiguous 128B Vt row -> conflict-free.
__global__ __launch_bounds__(256) void attn_kernel(const u16* __restrict__ qkv,
                                                   u16* __restrict__ y) {
  constexpr int W = 3072, HD = 64;
  const int h = blockIdx.y;
  const int qt = (int)gridDim.x - 1 - (int)blockIdx.x;  // big blocks dispatch first
  const int q0 = qt * 64;
  const int tid = threadIdx.x, wid = tid >> 6, lane = tid & 63;
  const int l16 = lane & 15, l4 = lane >> 4;

  __shared__ u16 Ks[2][64 * 64];    // K tile [key][d], XOR-swizzled columns (128B rows)
  __shared__ u16 Vt[2][64][72];     // V^T tile [d][key], row-contiguous writes
  __shared__ u16 Ps[4][16][72];     // per-wave P tile [qrow][key], XOR-swizzled cols

  // Q A-frags live in registers: A row = l16, k-octet = l4
  const u16* qrow = qkv + (size_t)(q0 + wid * 16 + l16) * W + h * HD;
  const bf16x8 qa0 = *(const bf16x8*)(qrow + l4 * 8);
  const bf16x8 qa1 = *(const bf16x8*)(qrow + 32 + l4 * 8);

  f32x4 o[4] = {};
  float mrow[4] = {-3e38f, -3e38f, -3e38f, -3e38f};
  float lrow[4] = {0.f, 0.f, 0.f, 0.f};

  auto stageK = [&](int buf, int k0) {
#pragma unroll
    for (int half = 0; half < 2; ++half) {
      int t = half * 256 + tid;
      int row = t >> 3, chunk = t & 7;              // 8 x 16B chunks per 128B row
      int srcChunk = chunk ^ (row & 7);             // pre-swizzle global source (rule 21)
      gload_lds16(qkv + (size_t)(k0 + row) * W + 1024 + h * HD + srcChunk * 8,
                  &Ks[buf][t * 8]);
    }
  };

  // prologue: stage tile 0 (V regs first so their vmcnt drains independently)
  {
    const u16* vsrc = qkv + (size_t)lane * W + 2048 + h * HD + wid * 16;
    u16x8 v0r = *(const u16x8*)vsrc;
    u16x8 v1r = *(const u16x8*)(vsrc + 8);
    stageK(0, 0);
#pragma unroll
    for (int i = 0; i < 8; ++i) Vt[0][wid * 16 + i][lane] = v0r[i];
#pragma unroll
    for (int i = 0; i < 8; ++i) Vt[0][wid * 16 + 8 + i][lane] = v1r[i];
  }
  __syncthreads();

  int cur = 0;
  for (int kv = 0; kv <= qt; ++kv) {
    const int k0 = kv * 64;
    const int nxt = cur ^ 1;
    const bool pf = (kv < qt);

    // prefetch next tile: V -> regs (issue now, consume after compute), K -> LDS[nxt]
    u16x8 v0n, v1n;
    if (pf) {
      const u16* vsrc = qkv + (size_t)(k0 + 64 + lane) * W + 2048 + h * HD + wid * 16;
      v0n = *(const u16x8*)vsrc;
      v1n = *(const u16x8*)(vsrc + 8);
      stageK(nxt, k0 + 64);
    }

    // S = Q K^T  (16 q-rows x 64 keys per wave); B frag: col(key)=l16, k-octet(d)=l4
    f32x4 s[4];
#pragma unroll
    for (int nb = 0; nb < 4; ++nb) {
      const int krow = nb * 16 + l16;
      const char* kbase = (const char*)&Ks[cur][0] + krow * 128;
      const int swz = (krow & 7) << 4;
      bf16x8 kb0 = *(const bf16x8*)(kbase + ((l4 * 16) ^ swz));
      bf16x8 kb1 = *(const bf16x8*)(kbase + ((64 + l4 * 16) ^ swz));
      f32x4 z = {0.f, 0.f, 0.f, 0.f};
      z = mfma16(qa0, kb0, z);
      s[nb] = mfma16(qa1, kb1, z);
    }

    // scale + causal mask + online softmax, log2 domain (rows = l4*4+j)
    constexpr float cl2 = 0.125f * 1.44269504f;   // scale * log2(e)
    float p[4][4];
    float rmax[4] = {-3e38f, -3e38f, -3e38f, -3e38f};
#pragma unroll
    for (int nb = 0; nb < 4; ++nb) {
      const int kcol = k0 + nb * 16 + l16;
#pragma unroll
      for (int j = 0; j < 4; ++j) {
        const int qr = q0 + wid * 16 + l4 * 4 + j;
        float v = s[nb][j] * cl2;
        v = (kcol <= qr) ? v : -3e38f;
        p[nb][j] = v;
        rmax[j] = fmaxf(rmax[j], v);
      }
    }
#pragma unroll
    for (int off = 1; off < 16; off <<= 1)
#pragma unroll
      for (int j = 0; j < 4; ++j)
        rmax[j] = fmaxf(rmax[j], __shfl_xor(rmax[j], off));

    // defer-rescale: only touch o[] when the running max actually grows (wave-uniform)
    float dmax = 0.f;
    float mnew[4];
#pragma unroll
    for (int j = 0; j < 4; ++j) {
      mnew[j] = fmaxf(mrow[j], rmax[j]);
      dmax = fmaxf(dmax, mnew[j] - mrow[j]);
    }
    if (__any(dmax > 0.f)) {
#pragma unroll
      for (int j = 0; j < 4; ++j) {
        const float scj = exp2f(mrow[j] - mnew[j]);   // first tile: exp2(-huge)=0
        mrow[j] = mnew[j];
        lrow[j] *= scj;
#pragma unroll
        for (int nb = 0; nb < 4; ++nb) o[nb][j] *= scj;
      }
    }
    float rsum[4] = {0.f, 0.f, 0.f, 0.f};
#pragma unroll
    for (int j = 0; j < 4; ++j)
#pragma unroll
      for (int nb = 0; nb < 4; ++nb) {
        const float e = exp2f(p[nb][j] - mrow[j]);    // masked -> exp2(-huge)=0
        p[nb][j] = e;
        rsum[j] += e;
      }
#pragma unroll
    for (int off = 1; off < 16; off <<= 1)
#pragma unroll
      for (int j = 0; j < 4; ++j)
        rsum[j] += __shfl_xor(rsum[j], off);
#pragma unroll
    for (int j = 0; j < 4; ++j) lrow[j] += rsum[j];

    // P: C-layout regs -> per-wave LDS (XOR-swizzled cols) -> A-layout frags
#pragma unroll
    for (int nb = 0; nb < 4; ++nb)
#pragma unroll
      for (int j = 0; j < 4; ++j) {
        const int r = l4 * 4 + j;
        Ps[wid][r][(nb * 16 + l16) ^ ((r & 7) << 3)] = f2bf(p[nb][j]);
      }
    const int pswz = (l16 & 7) << 3;
    const bf16x8 pa0 = *(const bf16x8*)&Ps[wid][l16][(l4 * 8) ^ pswz];
    const bf16x8 pa1 = *(const bf16x8*)&Ps[wid][l16][(32 + l4 * 8) ^ pswz];

    // O += P V : B frag from Vt rows: col(d)=l16(+16nb), k-octet(key)=l4
#pragma unroll
    for (int nb = 0; nb < 4; ++nb) {
      bf16x8 vb0 = *(const bf16x8*)&Vt[cur][nb * 16 + l16][l4 * 8];
      bf16x8 vb1 = *(const bf16x8*)&Vt[cur][nb * 16 + l16][32 + l4 * 8];
      o[nb] = mfma16(pa0, vb0, o[nb]);
      o[nb] = mfma16(pa1, vb1, o[nb]);
    }

    // deferred transposed V write for next tile: each instruction writes one
    // contiguous 128B Vt row (lane = key) -> 2 lanes/bank = conflict-free
    if (pf) {
#pragma unroll
      for (int i = 0; i < 8; ++i) Vt[nxt][wid * 16 + i][lane] = v0n[i];
#pragma unroll
      for (int i = 0; i < 8; ++i) Vt[nxt][wid * 16 + 8 + i][lane] = v1n[i];
    }
    __syncthreads();  // one barrier per tile: next K/V staged, this tile's reads done
    cur = nxt;
  }

  // epilogue: O /= l, write bf16 y[T][1024]
#pragma unroll
  for (int j = 0; j < 4; ++j) {
    const float inv = 1.0f / lrow[j];
    u16* yr = y + (size_t)(q0 + wid * 16 + l4 * 4 + j) * 1024 + h * HD;
#pragma unroll
    for (int nb = 0; nb < 4; ++nb)
      yr[nb * 16 + l16] = f2bf(o[nb][j] * inv);
  }
}

// ---------------- launch ----------------
extern "C" void kernel_launch(void* const* d_in, const int* in_sizes, int n_in,
                              void* d_out, int out_size, void* d_ws, size_t ws_size,
                              hipStream_t stream) {
  constexpr int T = 2048, D = 1024;
  const float* x    = (const float*)d_in[0];   // [T][D]
  const float* Wqkv = (const float*)d_in[1];   // [D][3D]
  const float* Wo   = (const float*)d_in[2];   // [D][D]
  float* out = (float*)d_out;                  // [T][D] f32

  u16* xb    = (u16*)d_ws;                     // [T][D]
  u16* WqkvT = xb + (size_t)T * D;             // [3D][D]
  u16* WoT   = WqkvT + (size_t)3 * D * D;      // [D][D]
  u16* qkv   = WoT + (size_t)D * D;            // [T][3D]
  u16* yb    = qkv + (size_t)T * 3 * D;        // [T][D]   (total 28 MB)

  cvt_bf16_kernel<<<(T * D) / (256 * 8), 256, 0, stream>>>(x, xb, T * D);
  transpose_bf16_kernel<<<dim3(3 * D / 32, D / 32), 256, 0, stream>>>(Wqkv, WqkvT, D, 3 * D);
  transpose_bf16_kernel<<<dim3(D / 32, D / 32), 256, 0, stream>>>(Wo, WoT, D, D);

  gemm_bt_kernel<u16><<<dim3(T / 128, 3 * D / 128), 256, 0, stream>>>(xb, WqkvT, qkv, T, 3 * D, D);
  attn_kernel<<<dim3(T / 64, 16), 256, 0, stream>>>(qkv, yb);
  gemm_bt_kernel<float><<<dim3(T / 128, D / 128), 256, 0, stream>>>(yb, WoT, out, T, D, D);
}

// Round 3
// 153.154 us; speedup vs baseline: 1.0049x; 1.0049x over previous
//
#include <hip/hip_runtime.h>
#include <hip/hip_bf16.h>

// Fused causal attention block for MI355X (gfx950).
// cvt(x) | transpose(Wqkv) | transpose(Wo) -> GEMM1(qkv) -> attn (KV-split) -> combine -> GEMM2
// All matmuls use v_mfma_f32_16x16x32_bf16 with f32 accumulation.

using u16 = unsigned short;
typedef __attribute__((ext_vector_type(8))) __bf16 bf16x8;      // 8 bf16 = 4 VGPR (MFMA A/B frag)
typedef __attribute__((ext_vector_type(8))) unsigned short u16x8;
typedef __attribute__((ext_vector_type(4))) float f32x4;        // MFMA C/D frag

__device__ __forceinline__ u16 f2bf(float f) {
  union { float f; unsigned u; } v; v.f = f;
  unsigned r = v.u + 0x7FFFu + ((v.u >> 16) & 1u);  // round-to-nearest-even
  return (u16)(r >> 16);
}

__device__ __forceinline__ void gload_lds16(const void* g, void* l) {
  __builtin_amdgcn_global_load_lds((const __attribute__((address_space(1))) void*)g,
                                   (__attribute__((address_space(3))) void*)l, 16, 0, 0);
}

__device__ __forceinline__ f32x4 mfma16(bf16x8 a, bf16x8 b, f32x4 c) {
  return __builtin_amdgcn_mfma_f32_16x16x32_bf16(a, b, c, 0, 0, 0);
}

// ---------------- f32 -> bf16 straight convert ----------------
__global__ __launch_bounds__(256) void cvt_bf16_kernel(const float* __restrict__ in,
                                                       u16* __restrict__ out, int n) {
  int i = (blockIdx.x * 256 + threadIdx.x) * 8;
  if (i >= n) return;
  float4 a = *(const float4*)(in + i);
  float4 b = *(const float4*)(in + i + 4);
  u16x8 r;
  r[0] = f2bf(a.x); r[1] = f2bf(a.y); r[2] = f2bf(a.z); r[3] = f2bf(a.w);
  r[4] = f2bf(b.x); r[5] = f2bf(b.y); r[6] = f2bf(b.z); r[7] = f2bf(b.w);
  *(u16x8*)(out + i) = r;
}

// ---------------- f32 [R][C] -> bf16 [C][R] transpose-convert ----------------
__global__ __launch_bounds__(256) void transpose_bf16_kernel(const float* __restrict__ in,
                                                             u16* __restrict__ out,
                                                             int R, int C) {
  __shared__ u16 tile[32][33];
  const int c0 = blockIdx.x * 32, r0 = blockIdx.y * 32;
  const int tx = threadIdx.x & 31, ty = threadIdx.x >> 5;
#pragma unroll
  for (int rr = ty; rr < 32; rr += 8)
    tile[rr][tx] = f2bf(in[(size_t)(r0 + rr) * C + (c0 + tx)]);
  __syncthreads();
#pragma unroll
  for (int rr = ty; rr < 32; rr += 8)
    out[(size_t)(c0 + rr) * R + (r0 + tx)] = tile[tx][rr];
}

// ---------------- bf16 GEMM, C[M][N] = A[M][K] * Bt[N][K]^T ----------------
template <typename OutT>
__global__ __launch_bounds__(256) void gemm_bt_kernel(const u16* __restrict__ A,
                                                      const u16* __restrict__ Bt,
                                                      OutT* __restrict__ C,
                                                      int M, int N, int K) {
  constexpr int BM = 128, BN = 128, BK = 32;
  __shared__ u16 As[2][BM * BK];
  __shared__ u16 Bs[2][BN * BK];
  const int tid = threadIdx.x;
  const int lane = tid & 63, wid = tid >> 6;
  const int l16 = lane & 15, l4 = lane >> 4;
  const int wr = (wid >> 1) * 64, wc = (wid & 1) * 64;
  const long bm = (long)blockIdx.x * BM, bn = (long)blockIdx.y * BN;

  f32x4 acc[4][4] = {};
  const int KT = K / BK;

  auto stage = [&](int buf, int kt) {
    const int k0 = kt * BK;
#pragma unroll
    for (int half = 0; half < 2; ++half) {
      int t = half * 256 + tid;
      int row = t >> 2, c8 = (t & 3) << 3;
      gload_lds16(A + (bm + row) * (size_t)K + k0 + c8, &As[buf][row * BK + c8]);
    }
#pragma unroll
    for (int half = 0; half < 2; ++half) {
      int t = half * 256 + tid;
      int row = t >> 2, c8 = (t & 3) << 3;
      gload_lds16(Bt + (bn + row) * (size_t)K + k0 + c8, &Bs[buf][row * BK + c8]);
    }
  };

  stage(0, 0);
  __syncthreads();
  int cur = 0;
  for (int kt = 0; kt < KT; ++kt) {
    if (kt + 1 < KT) stage(cur ^ 1, kt + 1);
    bf16x8 af[4], bfr[4];
#pragma unroll
    for (int m = 0; m < 4; ++m)
      af[m] = *(const bf16x8*)&As[cur][(wr + m * 16 + l16) * BK + l4 * 8];
#pragma unroll
    for (int n = 0; n < 4; ++n)
      bfr[n] = *(const bf16x8*)&Bs[cur][(wc + n * 16 + l16) * BK + l4 * 8];
#pragma unroll
    for (int m = 0; m < 4; ++m)
#pragma unroll
      for (int n = 0; n < 4; ++n)
        acc[m][n] = mfma16(af[m], bfr[n], acc[m][n]);
    __syncthreads();
    cur ^= 1;
  }

#pragma unroll
  for (int m = 0; m < 4; ++m) {
    const long row0 = bm + wr + m * 16 + l4 * 4;
#pragma unroll
    for (int n = 0; n < 4; ++n) {
      const long col = bn + wc + n * 16 + l16;
#pragma unroll
      for (int j = 0; j < 4; ++j) {
        float v = acc[m][n][j];
        if constexpr (sizeof(OutT) == 2)
          C[(row0 + j) * N + col] = (OutT)f2bf(v);
        else
          C[(row0 + j) * N + col] = (OutT)v;
      }
    }
  }
}

// ---------------- causal flash attention, KV-split (flash-decode) ----------------
// qkv: [T][3072] bf16 (Q at h*64, K at 1024+h*64, V at 2048+h*64).
// grid = (32 q-tiles, 16 heads, S splits). Block = 64 queries, 4 waves (16 q-rows each).
// Swapped QK^T: s = mfma(K,Q) so each lane holds 16 scores of ONE q-row (q = l16)
//   -> softmax reductions are in-register trees + 2 shfl_xor (over the l4 axis).
// SPLIT=true: write unnormalized partial o (f32) + (m,l) per row; combine_kernel merges.
template <bool SPLIT>
__global__ __launch_bounds__(256) void attn_kernel(const u16* __restrict__ qkv,
                                                   u16* __restrict__ y,
                                                   float* __restrict__ opart,
                                                   float2* __restrict__ ml,
                                                   int S) {
  constexpr int W = 3072, HD = 64;
  const int h = blockIdx.y;
  const int qt = 31 - (int)blockIdx.x;       // big q-tiles dispatch first
  const int s = blockIdx.z;
  const int q0 = qt * 64;
  const int tid = threadIdx.x, wid = tid >> 6, lane = tid & 63;
  const int l16 = lane & 15, l4 = lane >> 4;

  // split s covers kv tiles [t0, t1)
  const int per = (qt + S) / S;              // ceil((qt+1)/S)
  const int t0 = SPLIT ? s * per : 0;
  const int t1 = SPLIT ? min(t0 + per, qt + 1) : qt + 1;

  if (SPLIT && t0 >= t1) {                   // empty split: sentinel and exit
    if (tid < 64) ml[((size_t)(q0 + tid) * 16 + h) * S + s] = make_float2(-3e38f, 0.f);
    return;
  }

  __shared__ u16 Ks[2][64 * 64];    // K tile [key][d], XOR-swizzled columns (128B rows)
  __shared__ u16 Vt[2][64][72];     // V^T tile [d][key]
  __shared__ u16 Ps[4][16][72];     // per-wave P tile [qrow=l16][key], XOR-swizzled

  // Q frags (used as MFMA B operand in swapped QK): lane l16 = q-row, l4 = d-octet
  const u16* qrow = qkv + (size_t)(q0 + wid * 16 + l16) * W + h * HD;
  const bf16x8 qa0 = *(const bf16x8*)(qrow + l4 * 8);
  const bf16x8 qa1 = *(const bf16x8*)(qrow + 32 + l4 * 8);

  f32x4 o[4] = {};
  float mrow = -3e38f, lrow = 0.f;           // per-lane: q-row = l16 (replicated over l4)

  auto stageK = [&](int buf, int k0) {
#pragma unroll
    for (int half = 0; half < 2; ++half) {
      int t = half * 256 + tid;
      int row = t >> 3, chunk = t & 7;
      int srcChunk = chunk ^ (row & 7);      // pre-swizzle global source (rule 21)
      gload_lds16(qkv + (size_t)(k0 + row) * W + 1024 + h * HD + srcChunk * 8,
                  &Ks[buf][t * 8]);
    }
  };

  // prologue: stage tile t0
  {
    const u16* vsrc = qkv + (size_t)(t0 * 64 + lane) * W + 2048 + h * HD + wid * 16;
    u16x8 v0r = *(const u16x8*)vsrc;
    u16x8 v1r = *(const u16x8*)(vsrc + 8);
    stageK(0, t0 * 64);
#pragma unroll
    for (int i = 0; i < 8; ++i) Vt[0][wid * 16 + i][lane] = v0r[i];
#pragma unroll
    for (int i = 0; i < 8; ++i) Vt[0][wid * 16 + 8 + i][lane] = v1r[i];
  }
  __syncthreads();

  const int qr = q0 + wid * 16 + l16;        // this lane's q-row
  constexpr float cl2 = 0.125f * 1.44269504f; // scale * log2(e)

  int cur = 0;
  for (int kv = t0; kv < t1; ++kv) {
    const int k0 = kv * 64;
    const int nxt = cur ^ 1;
    const bool pf = (kv + 1 < t1);

    u16x8 v0n, v1n;
    if (pf) {
      const u16* vsrc = qkv + (size_t)(k0 + 64 + lane) * W + 2048 + h * HD + wid * 16;
      v0n = *(const u16x8*)vsrc;
      v1n = *(const u16x8*)(vsrc + 8);
      stageK(nxt, k0 + 64);
    }

    // S^T = K Q^T per 16-key tile: A = K rows (l16 = key, l4 = d-octet),
    // B = Q (l16 = q-col, l4 = d-octet). Output: row = key = l4*4+j, col = q = l16.
    f32x4 sv[4];
#pragma unroll
    for (int nb = 0; nb < 4; ++nb) {
      const int krow = nb * 16 + l16;
      const char* kbase = (const char*)&Ks[cur][0] + krow * 128;
      const int swz = (krow & 7) << 4;
      bf16x8 kb0 = *(const bf16x8*)(kbase + ((l4 * 16) ^ swz));
      bf16x8 kb1 = *(const bf16x8*)(kbase + ((64 + l4 * 16) ^ swz));
      f32x4 z = {0.f, 0.f, 0.f, 0.f};
      z = mfma16(kb0, qa0, z);
      sv[nb] = mfma16(kb1, qa1, z);
    }

    // scale (+ causal mask on diagonal tile only); all 16 values belong to q-row l16
    float p[4][4];
    const bool diag = (kv == qt);
#pragma unroll
    for (int nb = 0; nb < 4; ++nb)
#pragma unroll
      for (int j = 0; j < 4; ++j) {
        float v = sv[nb][j] * cl2;
        if (diag) {
          const int key = k0 + nb * 16 + l4 * 4 + j;
          v = (key <= qr) ? v : -3e38f;
        }
        p[nb][j] = v;
      }

    // row max: in-register tree + 2 cross-lane steps (l4 axis)
    float rmax = -3e38f;
#pragma unroll
    for (int nb = 0; nb < 4; ++nb)
#pragma unroll
      for (int j = 0; j < 4; ++j) rmax = fmaxf(rmax, p[nb][j]);
    rmax = fmaxf(rmax, __shfl_xor(rmax, 16));
    rmax = fmaxf(rmax, __shfl_xor(rmax, 32));

    const float mnew = fmaxf(mrow, rmax);
    if (__any(mnew > mrow)) {                 // defer-rescale (wave-uniform)
      const float sc = exp2f(mrow - mnew);    // first tile: exp2(-huge)=0
      mrow = mnew;
      lrow *= sc;
      float scj[4];
#pragma unroll
      for (int j = 0; j < 4; ++j) scj[j] = __shfl(sc, l4 * 4 + j);  // o rows = l4*4+j
#pragma unroll
      for (int nb = 0; nb < 4; ++nb)
#pragma unroll
        for (int j = 0; j < 4; ++j) o[nb][j] *= scj[j];
    }

    float rsum = 0.f;
#pragma unroll
    for (int nb = 0; nb < 4; ++nb)
#pragma unroll
      for (int j = 0; j < 4; ++j) {
        const float e = exp2f(p[nb][j] - mrow);
        p[nb][j] = e;
        rsum += e;
      }
    rsum += __shfl_xor(rsum, 16);
    rsum += __shfl_xor(rsum, 32);
    lrow += rsum;

    // P -> per-wave LDS: row = q = l16, 4 consecutive keys per packed b64 write
    const int pswz = (l16 & 7) << 3;
#pragma unroll
    for (int nb = 0; nb < 4; ++nb) {
      uint2 w;
      w.x = (unsigned)f2bf(p[nb][0]) | ((unsigned)f2bf(p[nb][1]) << 16);
      w.y = (unsigned)f2bf(p[nb][2]) | ((unsigned)f2bf(p[nb][3]) << 16);
      *(uint2*)&Ps[wid][l16][(nb * 16 + l4 * 4) ^ pswz] = w;
    }

    // deferred transposed V write for next tile (conflict-free contiguous rows)
    if (pf) {
#pragma unroll
      for (int i = 0; i < 8; ++i) Vt[nxt][wid * 16 + i][lane] = v0n[i];
#pragma unroll
      for (int i = 0; i < 8; ++i) Vt[nxt][wid * 16 + 8 + i][lane] = v1n[i];
    }

    // P A-frag: row = q = l16, key-octet = l4 (intra-wave LDS round trip)
    const bf16x8 pa0 = *(const bf16x8*)&Ps[wid][l16][(l4 * 8) ^ pswz];
    const bf16x8 pa1 = *(const bf16x8*)&Ps[wid][l16][(32 + l4 * 8) ^ pswz];

    // O += P V : B frag from Vt rows: col(d) = l16+16nb, key-octet = l4
#pragma unroll
    for (int nb = 0; nb < 4; ++nb) {
      bf16x8 vb0 = *(const bf16x8*)&Vt[cur][nb * 16 + l16][l4 * 8];
      bf16x8 vb1 = *(const bf16x8*)&Vt[cur][nb * 16 + l16][32 + l4 * 8];
      o[nb] = mfma16(pa0, vb0, o[nb]);
      o[nb] = mfma16(pa1, vb1, o[nb]);
    }
    __syncthreads();
    cur = nxt;
  }

  if constexpr (SPLIT) {
    // unnormalized partial O (f32) + per-row (m, l)
#pragma unroll
    for (int j = 0; j < 4; ++j) {
      const size_t q = q0 + wid * 16 + l4 * 4 + j;
      float* orow = opart + ((q * 16 + h) * S + s) * 64;
#pragma unroll
      for (int nb = 0; nb < 4; ++nb) orow[nb * 16 + l16] = o[nb][j];
    }
    if (l4 == 0)
      ml[((size_t)(q0 + wid * 16 + l16) * 16 + h) * S + s] = make_float2(mrow, lrow);
  } else {
    float inv[4];
#pragma unroll
    for (int j = 0; j < 4; ++j) inv[j] = __shfl(1.0f / lrow, l4 * 4 + j);
#pragma unroll
    for (int j = 0; j < 4; ++j) {
      u16* yr = y + (size_t)(q0 + wid * 16 + l4 * 4 + j) * 1024 + h * HD;
#pragma unroll
      for (int nb = 0; nb < 4; ++nb)
        yr[nb * 16 + l16] = f2bf(o[nb][j] * inv[j]);
    }
  }
}

// ---------------- merge KV-split partials ----------------
// thread <-> (p = q*16+h, d); y[q][h*64+d] = sum_s w_s o_s / sum_s w_s l_s, w_s = 2^(m_s-M)
__global__ __launch_bounds__(256) void combine_kernel(const float* __restrict__ opart,
                                                      const float2* __restrict__ ml,
                                                      u16* __restrict__ y, int S) {
  const int p = blockIdx.x * 4 + (threadIdx.x >> 6);
  const int d = threadIdx.x & 63;
  float M = -3e38f;
  for (int s = 0; s < S; ++s) M = fmaxf(M, ml[(size_t)p * S + s].x);
  float num = 0.f, den = 0.f;
  for (int s = 0; s < S; ++s) {
    const float2 m2 = ml[(size_t)p * S + s];
    const float w = exp2f(m2.x - M);          // sentinel m=-3e38 -> w=0
    num += w * opart[((size_t)p * S + s) * 64 + d];
    den += w * m2.y;
  }
  const int q = p >> 4, h = p & 15;
  y[(size_t)q * 1024 + h * 64 + d] = f2bf(num / den);
}

// ---------------- launch ----------------
extern "C" void kernel_launch(void* const* d_in, const int* in_sizes, int n_in,
                              void* d_out, int out_size, void* d_ws, size_t ws_size,
                              hipStream_t stream) {
  constexpr int T = 2048, D = 1024;
  const float* x    = (const float*)d_in[0];   // [T][D]
  const float* Wqkv = (const float*)d_in[1];   // [D][3D]
  const float* Wo   = (const float*)d_in[2];   // [D][D]
  float* out = (float*)d_out;                  // [T][D] f32

  u16* xb    = (u16*)d_ws;                     // [T][D]
  u16* WqkvT = xb + (size_t)T * D;             // [3D][D]
  u16* WoT   = WqkvT + (size_t)3 * D * D;      // [D][D]
  u16* qkv   = WoT + (size_t)D * D;            // [T][3D]
  u16* yb    = qkv + (size_t)T * 3 * D;        // [T][D]   (28 MB so far)

  const size_t baseB = (size_t)(T * D + 3 * D * D + D * D + T * 3 * D + T * D) * 2;
  auto needB = [&](int S) {
    return baseB + (size_t)T * 16 * S * 64 * 4 + (size_t)T * 16 * S * 8;
  };
  int S = 1;
  if (ws_size >= needB(4)) S = 4;
  else if (ws_size >= needB(2)) S = 2;

  cvt_bf16_kernel<<<(T * D) / (256 * 8), 256, 0, stream>>>(x, xb, T * D);
  transpose_bf16_kernel<<<dim3(3 * D / 32, D / 32), 256, 0, stream>>>(Wqkv, WqkvT, D, 3 * D);
  transpose_bf16_kernel<<<dim3(D / 32, D / 32), 256, 0, stream>>>(Wo, WoT, D, D);

  gemm_bt_kernel<u16><<<dim3(T / 128, 3 * D / 128), 256, 0, stream>>>(xb, WqkvT, qkv, T, 3 * D, D);

  if (S > 1) {
    float*  opart = (float*)((char*)d_ws + baseB);
    float2* ml    = (float2*)(opart + (size_t)T * 16 * S * 64);
    attn_kernel<true><<<dim3(T / 64, 16, S), 256, 0, stream>>>(qkv, nullptr, opart, ml, S);
    combine_kernel<<<T * 16 / 4, 256, 0, stream>>>(opart, ml, yb, S);
  } else {
    attn_kernel<false><<<dim3(T / 64, 16, 1), 256, 0, stream>>>(qkv, yb, nullptr, nullptr, 1);
  }

  gemm_bt_kernel<float><<<dim3(T / 128, D / 128), 256, 0, stream>>>(yb, WoT, out, T, D, D);
}

// Round 4
// 131.585 us; speedup vs baseline: 1.1697x; 1.1639x over previous
//
#include <hip/hip_runtime.h>
#include <hip/hip_bf16.h>

// Fused causal attention block for MI355X (gfx950).
// cvt(x) | transpose(Wqkv) | transpose(Wo) -> GEMM1(qkv) -> attn (paired+split) -> combine -> GEMM2
// All matmuls use v_mfma_f32_16x16x32_bf16 with f32 accumulation.

using u16 = unsigned short;
typedef __attribute__((ext_vector_type(8))) __bf16 bf16x8;      // 8 bf16 = 4 VGPR (MFMA A/B frag)
typedef __attribute__((ext_vector_type(8))) unsigned short u16x8;
typedef __attribute__((ext_vector_type(4))) float f32x4;        // MFMA C/D frag

__device__ __forceinline__ u16 f2bf(float f) {
  union { float f; unsigned u; } v; v.f = f;
  unsigned r = v.u + 0x7FFFu + ((v.u >> 16) & 1u);  // round-to-nearest-even
  return (u16)(r >> 16);
}

__device__ __forceinline__ void gload_lds16(const void* g, void* l) {
  __builtin_amdgcn_global_load_lds((const __attribute__((address_space(1))) void*)g,
                                   (__attribute__((address_space(3))) void*)l, 16, 0, 0);
}

__device__ __forceinline__ f32x4 mfma16(bf16x8 a, bf16x8 b, f32x4 c) {
  return __builtin_amdgcn_mfma_f32_16x16x32_bf16(a, b, c, 0, 0, 0);
}

// ---------------- f32 -> bf16 straight convert ----------------
__global__ __launch_bounds__(256) void cvt_bf16_kernel(const float* __restrict__ in,
                                                       u16* __restrict__ out, int n) {
  int i = (blockIdx.x * 256 + threadIdx.x) * 8;
  if (i >= n) return;
  float4 a = *(const float4*)(in + i);
  float4 b = *(const float4*)(in + i + 4);
  u16x8 r;
  r[0] = f2bf(a.x); r[1] = f2bf(a.y); r[2] = f2bf(a.z); r[3] = f2bf(a.w);
  r[4] = f2bf(b.x); r[5] = f2bf(b.y); r[6] = f2bf(b.z); r[7] = f2bf(b.w);
  *(u16x8*)(out + i) = r;
}

// ---------------- f32 [R][C] -> bf16 [C][R] transpose-convert ----------------
__global__ __launch_bounds__(256) void transpose_bf16_kernel(const float* __restrict__ in,
                                                             u16* __restrict__ out,
                                                             int R, int C) {
  __shared__ u16 tile[32][33];
  const int c0 = blockIdx.x * 32, r0 = blockIdx.y * 32;
  const int tx = threadIdx.x & 31, ty = threadIdx.x >> 5;
#pragma unroll
  for (int rr = ty; rr < 32; rr += 8)
    tile[rr][tx] = f2bf(in[(size_t)(r0 + rr) * C + (c0 + tx)]);
  __syncthreads();
#pragma unroll
  for (int rr = ty; rr < 32; rr += 8)
    out[(size_t)(c0 + rr) * R + (r0 + tx)] = tile[tx][rr];
}

// ---------------- bf16 GEMM, C[M][N] = A[M][K] * Bt[N][K]^T ----------------
template <typename OutT>
__global__ __launch_bounds__(256) void gemm_bt_kernel(const u16* __restrict__ A,
                                                      const u16* __restrict__ Bt,
                                                      OutT* __restrict__ C,
                                                      int M, int N, int K) {
  constexpr int BM = 128, BN = 128, BK = 32;
  __shared__ u16 As[2][BM * BK];
  __shared__ u16 Bs[2][BN * BK];
  const int tid = threadIdx.x;
  const int lane = tid & 63, wid = tid >> 6;
  const int l16 = lane & 15, l4 = lane >> 4;
  const int wr = (wid >> 1) * 64, wc = (wid & 1) * 64;
  const long bm = (long)blockIdx.x * BM, bn = (long)blockIdx.y * BN;

  f32x4 acc[4][4] = {};
  const int KT = K / BK;

  auto stage = [&](int buf, int kt) {
    const int k0 = kt * BK;
#pragma unroll
    for (int half = 0; half < 2; ++half) {
      int t = half * 256 + tid;
      int row = t >> 2, c8 = (t & 3) << 3;
      gload_lds16(A + (bm + row) * (size_t)K + k0 + c8, &As[buf][row * BK + c8]);
    }
#pragma unroll
    for (int half = 0; half < 2; ++half) {
      int t = half * 256 + tid;
      int row = t >> 2, c8 = (t & 3) << 3;
      gload_lds16(Bt + (bn + row) * (size_t)K + k0 + c8, &Bs[buf][row * BK + c8]);
    }
  };

  stage(0, 0);
  __syncthreads();
  int cur = 0;
  for (int kt = 0; kt < KT; ++kt) {
    if (kt + 1 < KT) stage(cur ^ 1, kt + 1);
    bf16x8 af[4], bfr[4];
#pragma unroll
    for (int m = 0; m < 4; ++m)
      af[m] = *(const bf16x8*)&As[cur][(wr + m * 16 + l16) * BK + l4 * 8];
#pragma unroll
    for (int n = 0; n < 4; ++n)
      bfr[n] = *(const bf16x8*)&Bs[cur][(wc + n * 16 + l16) * BK + l4 * 8];
#pragma unroll
    for (int m = 0; m < 4; ++m)
#pragma unroll
      for (int n = 0; n < 4; ++n)
        acc[m][n] = mfma16(af[m], bfr[n], acc[m][n]);
    __syncthreads();
    cur ^= 1;
  }

#pragma unroll
  for (int m = 0; m < 4; ++m) {
    const long row0 = bm + wr + m * 16 + l4 * 4;
#pragma unroll
    for (int n = 0; n < 4; ++n) {
      const long col = bn + wc + n * 16 + l16;
#pragma unroll
      for (int j = 0; j < 4; ++j) {
        float v = acc[m][n][j];
        if constexpr (sizeof(OutT) == 2)
          C[(row0 + j) * N + col] = (OutT)f2bf(v);
        else
          C[(row0 + j) * N + col] = (OutT)v;
      }
    }
  }
}

// ---------------- causal flash attention: diagonal-paired + KV-split ----------------
// qkv: [T][3072] bf16 (Q at h*64, K at 1024+h*64, V at 2048+h*64).
// Block (p,h,s): handles q-tiles p and 31-p (33 KV-tiles total), split s of S over that
// work list -> every block runs ceil/floor(33/S) tiles: perfectly balanced.
// K frags are read DIRECTLY from global (L2-hot, 8KB/head tile) - no K LDS, no stage drain.
// V double-buffered in LDS as V^T (register transpose, row-contiguous conflict-free writes,
// write deferred past PV = T14). One barrier per tile. LDS 25KB -> 6 blocks/CU.
// Swapped QK^T: sv = mfma(K,Q) so lane holds 16 scores of q-row l16 -> in-register softmax.
__global__ __launch_bounds__(256, 5) void attn_kernel(const u16* __restrict__ qkv,
                                                      float* __restrict__ opart,
                                                      float2* __restrict__ ml, int S) {
  constexpr int W = 3072;
  const int p = blockIdx.x, h = blockIdx.y, s = blockIdx.z;
  const int tid = threadIdx.x, wid = tid >> 6, lane = tid & 63;
  const int l16 = lane & 15, l4 = lane >> 4;
  const int w0 = (33 * s) / S, w1 = (33 * (s + 1)) / S;   // work items in [w0,w1)

  __shared__ u16 Vt[2][64][66];     // V^T tile [d][key], dbuf; 66-pad -> banks spread
  __shared__ u16 Ps[4][16][64];     // per-wave P tile [q=l16][key], XOR-swizzled cols

  constexpr float cl2 = 0.125f * 1.44269504f;   // scale * log2(e)
  const int pswz = (l16 & 7) << 3;

  bool didA = false, didB = false;
  int w = w0;
  while (w < w1) {
    const bool isA = (w <= p);                 // item w<=p: q-tile p, kv=w; else 31-p
    const int qt = isA ? p : 31 - p;
    const int wend = isA ? ((w1 < p + 1) ? w1 : (p + 1)) : w1;
    const int kvb = isA ? 0 : p + 1;           // kv = w - kvb
    if (isA) didA = true; else didB = true;

    const int q0 = qt * 64;
    const int qr = q0 + wid * 16 + l16;        // this lane's q-row (softmax axis)

    // Q frags (MFMA B operand): col(q)=l16, d-octet=l4
    const u16* qrow = qkv + (size_t)(q0 + wid * 16 + l16) * W + h * 64;
    const bf16x8 qa0 = *(const bf16x8*)(qrow + l4 * 8);
    const bf16x8 qa1 = *(const bf16x8*)(qrow + 32 + l4 * 8);

    f32x4 o[4] = {};
    float mrow = -3e38f, lrow = 0.f;

    // prologue: stage V tile (w-kvb) into Vt[0] (thread: key=lane, d-group=wid)
    {
      const int k0 = (w - kvb) * 64;
      const u16* vsrc = qkv + (size_t)(k0 + lane) * W + 2048 + h * 64 + wid * 16;
      u16x8 a = *(const u16x8*)vsrc;
      u16x8 b = *(const u16x8*)(vsrc + 8);
#pragma unroll
      for (int i = 0; i < 8; ++i) Vt[0][wid * 16 + i][lane] = a[i];
#pragma unroll
      for (int i = 0; i < 8; ++i) Vt[0][wid * 16 + 8 + i][lane] = b[i];
      __syncthreads();
    }

    int cur = 0;
    for (; w < wend; ++w) {
      const int kv = w - kvb;
      const int k0 = kv * 64;
      const bool pf = (w + 1 < wend);

      // prefetch next V tile to regs (consumed after PV)
      u16x8 va, vb2;
      if (pf) {
        const u16* vsrc = qkv + (size_t)(k0 + 64 + lane) * W + 2048 + h * 64 + wid * 16;
        va = *(const u16x8*)vsrc;
        vb2 = *(const u16x8*)(vsrc + 8);
      }

      // S^T = K Q^T: A = K rows direct from global (row=key=l16+16nb, d-octet=l4)
      f32x4 sv[4];
#pragma unroll
      for (int nb = 0; nb < 4; ++nb) {
        const u16* krow = qkv + (size_t)(k0 + nb * 16 + l16) * W + 1024 + h * 64;
        bf16x8 kb0 = *(const bf16x8*)(krow + l4 * 8);
        bf16x8 kb1 = *(const bf16x8*)(krow + 32 + l4 * 8);
        f32x4 z = {0.f, 0.f, 0.f, 0.f};
        z = mfma16(kb0, qa0, z);
        sv[nb] = mfma16(kb1, qa1, z);
      }

      // scale (+ causal mask only on the diagonal tile); all 16 values are q-row l16
      float pv[4][4];
      const bool diag = (kv == qt);
#pragma unroll
      for (int nb = 0; nb < 4; ++nb)
#pragma unroll
        for (int j = 0; j < 4; ++j) {
          float v = sv[nb][j] * cl2;
          if (diag) {
            const int key = k0 + nb * 16 + l4 * 4 + j;
            v = (key <= qr) ? v : -3e38f;
          }
          pv[nb][j] = v;
        }

      // row max: in-register tree + 2 cross-lane steps (l4 axis)
      float rmax = -3e38f;
#pragma unroll
      for (int nb = 0; nb < 4; ++nb)
#pragma unroll
        for (int j = 0; j < 4; ++j) rmax = fmaxf(rmax, pv[nb][j]);
      rmax = fmaxf(rmax, __shfl_xor(rmax, 16));
      rmax = fmaxf(rmax, __shfl_xor(rmax, 32));

      const float mnew = fmaxf(mrow, rmax);
      if (__any(mnew > mrow)) {                // defer-rescale (wave-uniform)
        const float sc = exp2f(mrow - mnew);   // first tile: exp2(-huge)=0
        mrow = mnew;
        lrow *= sc;
        float scj[4];
#pragma unroll
        for (int j = 0; j < 4; ++j) scj[j] = __shfl(sc, l4 * 4 + j);  // o rows = l4*4+j
#pragma unroll
        for (int nb = 0; nb < 4; ++nb)
#pragma unroll
          for (int j = 0; j < 4; ++j) o[nb][j] *= scj[j];
      }

      float rsum = 0.f;
#pragma unroll
      for (int nb = 0; nb < 4; ++nb)
#pragma unroll
        for (int j = 0; j < 4; ++j) {
          const float e = exp2f(pv[nb][j] - mrow);
          pv[nb][j] = e;
          rsum += e;
        }
      rsum += __shfl_xor(rsum, 16);
      rsum += __shfl_xor(rsum, 32);
      lrow += rsum;

      // P: C-layout regs -> per-wave LDS (XOR-swizzled) -> A-layout frags (intra-wave)
#pragma unroll
      for (int nb = 0; nb < 4; ++nb) {
        uint2 wr2;
        wr2.x = (unsigned)f2bf(pv[nb][0]) | ((unsigned)f2bf(pv[nb][1]) << 16);
        wr2.y = (unsigned)f2bf(pv[nb][2]) | ((unsigned)f2bf(pv[nb][3]) << 16);
        *(uint2*)&Ps[wid][l16][(nb * 16 + l4 * 4) ^ pswz] = wr2;
      }
      const bf16x8 pa0 = *(const bf16x8*)&Ps[wid][l16][(l4 * 8) ^ pswz];
      const bf16x8 pa1 = *(const bf16x8*)&Ps[wid][l16][(32 + l4 * 8) ^ pswz];

      // O += P V : B frag from Vt rows: col(d)=nb*16+l16, key-octet=l4
#pragma unroll
      for (int nb = 0; nb < 4; ++nb) {
        bf16x8 vb0 = *(const bf16x8*)&Vt[cur][nb * 16 + l16][l4 * 8];
        bf16x8 vb1 = *(const bf16x8*)&Vt[cur][nb * 16 + l16][32 + l4 * 8];
        o[nb] = mfma16(pa0, vb0, o[nb]);
        o[nb] = mfma16(pa1, vb1, o[nb]);
      }

      // deferred transposed V write -> other buffer (contiguous rows, conflict-free)
      if (pf) {
#pragma unroll
        for (int i = 0; i < 8; ++i) Vt[cur ^ 1][wid * 16 + i][lane] = va[i];
#pragma unroll
        for (int i = 0; i < 8; ++i) Vt[cur ^ 1][wid * 16 + 8 + i][lane] = vb2[i];
      }
      __syncthreads();     // one barrier/tile: next V staged & this tile's reads done
      cur ^= 1;
    }

    // flush unnormalized partial O (f32) + (m,l) for q-tile qt, slot s
#pragma unroll
    for (int j = 0; j < 4; ++j) {
      const size_t q = q0 + wid * 16 + l4 * 4 + j;
      float* orow = opart + ((q * 16 + h) * S + s) * 64;
#pragma unroll
      for (int nb = 0; nb < 4; ++nb) orow[nb * 16 + l16] = o[nb][j];
    }
    if (l4 == 0)
      ml[((size_t)(q0 + wid * 16 + l16) * 16 + h) * S + s] = make_float2(mrow, lrow);
  }

  // untouched q-tile of this pair: sentinel so combine sees weight 0
  if (!didA && tid < 64)
    ml[((size_t)(p * 64 + tid) * 16 + h) * S + s] = make_float2(-3e38f, 0.f);
  if (!didB && tid < 64)
    ml[((size_t)((31 - p) * 64 + tid) * 16 + h) * S + s] = make_float2(-3e38f, 0.f);
}

// ---------------- merge KV-split partials ----------------
// thread <-> (p = q*16+h, d); y[q][h*64+d] = sum_s w_s o_s / sum_s w_s l_s, w_s = 2^(m_s-M)
__global__ __launch_bounds__(256) void combine_kernel(const float* __restrict__ opart,
                                                      const float2* __restrict__ ml,
                                                      u16* __restrict__ y, int S) {
  const int p = blockIdx.x * 4 + (threadIdx.x >> 6);
  const int d = threadIdx.x & 63;
  float M = -3e38f;
  for (int s = 0; s < S; ++s) M = fmaxf(M, ml[(size_t)p * S + s].x);
  float num = 0.f, den = 0.f;
  for (int s = 0; s < S; ++s) {
    const float2 m2 = ml[(size_t)p * S + s];
    const float w = exp2f(m2.x - M);          // sentinel m=-3e38 -> w=0
    num += w * opart[((size_t)p * S + s) * 64 + d];
    den += w * m2.y;
  }
  const int q = p >> 4, h = p & 15;
  y[(size_t)q * 1024 + h * 64 + d] = f2bf(num / den);
}

// ---------------- launch ----------------
extern "C" void kernel_launch(void* const* d_in, const int* in_sizes, int n_in,
                              void* d_out, int out_size, void* d_ws, size_t ws_size,
                              hipStream_t stream) {
  constexpr int T = 2048, D = 1024;
  const float* x    = (const float*)d_in[0];   // [T][D]
  const float* Wqkv = (const float*)d_in[1];   // [D][3D]
  const float* Wo   = (const float*)d_in[2];   // [D][D]
  float* out = (float*)d_out;                  // [T][D] f32

  u16* xb    = (u16*)d_ws;                     // [T][D]
  u16* WqkvT = xb + (size_t)T * D;             // [3D][D]
  u16* WoT   = WqkvT + (size_t)3 * D * D;      // [D][D]
  u16* qkv   = WoT + (size_t)D * D;            // [T][3D]
  u16* yb    = qkv + (size_t)T * 3 * D;        // [T][D]   (28 MB so far)

  const size_t baseB = (size_t)(T * D + 3 * D * D + D * D + T * 3 * D + T * D) * 2;
  auto needB = [&](int S) {
    return baseB + (size_t)T * 16 * S * 64 * 4 + (size_t)T * 16 * S * 8;
  };
  const int S = (ws_size >= needB(4)) ? 4 : 2;
  float*  opart = (float*)((char*)d_ws + baseB);
  float2* ml    = (float2*)(opart + (size_t)T * 16 * S * 64);

  cvt_bf16_kernel<<<(T * D) / (256 * 8), 256, 0, stream>>>(x, xb, T * D);
  transpose_bf16_kernel<<<dim3(3 * D / 32, D / 32), 256, 0, stream>>>(Wqkv, WqkvT, D, 3 * D);
  transpose_bf16_kernel<<<dim3(D / 32, D / 32), 256, 0, stream>>>(Wo, WoT, D, D);

  gemm_bt_kernel<u16><<<dim3(T / 128, 3 * D / 128), 256, 0, stream>>>(xb, WqkvT, qkv, T, 3 * D, D);

  attn_kernel<<<dim3(16, 16, S), 256, 0, stream>>>(qkv, opart, ml, S);
  combine_kernel<<<T * 16 / 4, 256, 0, stream>>>(opart, ml, yb, S);

  gemm_bt_kernel<float><<<dim3(T / 128, D / 128), 256, 0, stream>>>(yb, WoT, out, T, D, D);
}